// Round 1
// baseline (1273.591 us; speedup 1.0000x reference)
//
#include <hip/hip_runtime.h>
#include <hip/hip_bf16.h>
#include <cmath>

typedef unsigned short u16;
typedef __attribute__((ext_vector_type(8))) short bf16x8;
typedef __attribute__((ext_vector_type(4))) float f32x4;

#define B_    2
#define S_    2048
#define H_    4096
#define NH_   32
#define NKV_  8
#define HD_   128
#define WIN_  1024

__device__ __forceinline__ u16 f2b(float f) {
  union { float f; unsigned u; } v; v.f = f;
  unsigned r = v.u + 0x7fffu + ((v.u >> 16) & 1u);
  return (u16)(r >> 16);
}
__device__ __forceinline__ float b2f(u16 h) {
  union { unsigned u; float f; } v; v.u = ((unsigned)h) << 16;
  return v.f;
}

__device__ __forceinline__ void storeC(float* p, float v) { *p = v; }
__device__ __forceinline__ void storeC(u16* p, float v)   { *p = f2b(v); }

// ---------------- fp32 -> bf16 conversion ----------------
__global__ __launch_bounds__(256) void cvt_bf16(const float* __restrict__ s,
                                                u16* __restrict__ d, int n4) {
  int i = blockIdx.x * 256 + threadIdx.x;
  if (i < n4) {
    float4 v = ((const float4*)s)[i];
    ushort4 o;
    o.x = f2b(v.x); o.y = f2b(v.y); o.z = f2b(v.z); o.w = f2b(v.w);
    ((ushort4*)d)[i] = o;
  }
}

// ---------------- GEMM: C[M,N] = A[M,K] * W[N,K]^T (bf16 in, OutT out) -----
// 128x128 tile, BK=32, 4 waves (2x2), each wave 64x64 via 4x4 16x16x32 MFMAs.
template <typename OutT>
__global__ __launch_bounds__(256) void gemm_bt(const u16* __restrict__ A,
                                               const u16* __restrict__ W,
                                               OutT* __restrict__ C,
                                               int M, int N, int K) {
  constexpr int LDA = 40;  // 32 + 8 pad (16B) -> conflict-free b128 reads
  __shared__ u16 As[128 * LDA];
  __shared__ u16 Bs[128 * LDA];
  const int t = threadIdx.x;
  const int lane = t & 63, wave = t >> 6;
  const int quad = lane >> 4, l16 = lane & 15;
  const int wm = wave >> 1, wn = wave & 1;
  const size_t m0 = (size_t)blockIdx.y * 128, n0 = (size_t)blockIdx.x * 128;

  f32x4 acc[4][4] = {};
  const int row_s = t >> 2, kc = t & 3;  // 4 x 16B chunks per 64B row

  for (int k0 = 0; k0 < K; k0 += 32) {
    __syncthreads();
#pragma unroll
    for (int i = 0; i < 2; i++) {
      int row = row_s + i * 64;
      uint4 va = *(const uint4*)(A + (m0 + row) * K + k0 + kc * 8);
      *(uint4*)(&As[row * LDA + kc * 8]) = va;
      uint4 vb = *(const uint4*)(W + (n0 + row) * K + k0 + kc * 8);
      *(uint4*)(&Bs[row * LDA + kc * 8]) = vb;
    }
    __syncthreads();
    bf16x8 af[4], bfr[4];
#pragma unroll
    for (int i = 0; i < 4; i++) {
      af[i]  = *(const bf16x8*)(&As[(wm * 64 + i * 16 + l16) * LDA + quad * 8]);
      bfr[i] = *(const bf16x8*)(&Bs[(wn * 64 + i * 16 + l16) * LDA + quad * 8]);
    }
#pragma unroll
    for (int mi = 0; mi < 4; mi++)
#pragma unroll
      for (int nj = 0; nj < 4; nj++)
        acc[mi][nj] = __builtin_amdgcn_mfma_f32_16x16x32_bf16(
            af[mi], bfr[nj], acc[mi][nj], 0, 0, 0);
  }

#pragma unroll
  for (int mi = 0; mi < 4; mi++) {
    size_t rbase = m0 + wm * 64 + mi * 16 + quad * 4;
#pragma unroll
    for (int nj = 0; nj < 4; nj++) {
      size_t col = n0 + wn * 64 + nj * 16 + l16;
#pragma unroll
      for (int e = 0; e < 4; e++)
        storeC(&C[(rbase + e) * N + col], acc[mi][nj][e]);
    }
  }
}

// ---------------- RoPE in-place on bf16 [B,S,nheads,128] ----------------
__global__ __launch_bounds__(64) void rope_k(u16* __restrict__ X,
                                             const int* __restrict__ pos,
                                             int nheads) {
  int i = threadIdx.x;  // 0..63 freq index
  int h = blockIdx.x, s = blockIdx.y, b = blockIdx.z;
  int p = pos[b * S_ + s];
  float inv = expf(-((float)(2 * i) * (1.0f / 128.0f)) * logf(10000.0f));
  float ang = (float)p * inv;
  float c = cosf(ang), sn = sinf(ang);
  size_t base = (((size_t)(b * S_ + s)) * nheads + h) * HD_;
  float x1 = b2f(X[base + i]), x2 = b2f(X[base + i + 64]);
  X[base + i]      = f2b(x1 * c - x2 * sn);
  X[base + i + 64] = f2b(x2 * c + x1 * sn);
}

// ---------------- flash attention, sliding window ----------------
// grid (S/64, NH, B), 256 threads; wave w handles 16 q rows.
__global__ __launch_bounds__(256) void attn_k(const u16* __restrict__ Q,
                                              const u16* __restrict__ K,
                                              const u16* __restrict__ V,
                                              u16* __restrict__ O) {
  __shared__ u16 Ks[32 * 136];     // [key][d], pad 8
  __shared__ u16 Vs[128 * 40];     // [d][key], pad 8
  __shared__ u16 Ps[4][16 * 40];   // per-wave P scratch [q][key], pad 8

  const int t = threadIdx.x, wave = t >> 6, lane = t & 63;
  const int quad = lane >> 4, l16 = lane & 15;
  const int q0 = blockIdx.x * 64, h = blockIdx.y, b = blockIdx.z;
  const int hk = h >> 2;
  const int qw = q0 + wave * 16;
  const float scale = 0.08838834764831845f;  // 1/sqrt(128)

  // Q fragments: A[m=l16][k=quad*8+j] over k=0..127 (4 frags)
  bf16x8 qf[4];
  {
    size_t qrow = (((size_t)(b * S_ + qw + l16)) * NH_ + h) * HD_;
#pragma unroll
    for (int kk = 0; kk < 4; kk++)
      qf[kk] = *(const bf16x8*)(Q + qrow + kk * 32 + quad * 8);
  }

  f32x4 o_acc[8] = {};
  float m_i[4], l_i[4];
#pragma unroll
  for (int e = 0; e < 4; e++) { m_i[e] = -1e30f; l_i[e] = 0.0f; }

  int lo = q0 - (WIN_ - 1); if (lo < 0) lo = 0;
  const int lo_t = lo & ~31;

  for (int kt = lo_t; kt <= q0 + 63; kt += 32) {
    __syncthreads();  // protect previous tile reads
    // stage K tile [32][128]
#pragma unroll
    for (int i = 0; i < 2; i++) {
      int c = t + 256 * i;
      int row = c >> 4, dc = c & 15;
      uint4 v = *(const uint4*)(K + (((size_t)(b * S_ + kt + row)) * NKV_ + hk) * HD_ + dc * 8);
      *(uint4*)(&Ks[row * 136 + dc * 8]) = v;
    }
    // stage V transposed -> Vs[d][key]
#pragma unroll
    for (int i = 0; i < 2; i++) {
      int c = t + 256 * i;
      int row = c >> 4, dc = c & 15;
      uint4 v = *(const uint4*)(V + (((size_t)(b * S_ + kt + row)) * NKV_ + hk) * HD_ + dc * 8);
      const u16* pv = (const u16*)&v;
#pragma unroll
      for (int j = 0; j < 8; j++) Vs[(dc * 8 + j) * 40 + row] = pv[j];
    }
    __syncthreads();

    if (kt <= qw + 15 && kt + 31 >= qw - (WIN_ - 1)) {
      // S = Q K^T : two 16x16 score tiles (keys kt..+15, kt+16..+31)
      f32x4 s0 = {}, s1 = {};
#pragma unroll
      for (int kk = 0; kk < 4; kk++) {
        bf16x8 b0 = *(const bf16x8*)(&Ks[(l16) * 136 + kk * 32 + quad * 8]);
        bf16x8 b1 = *(const bf16x8*)(&Ks[(16 + l16) * 136 + kk * 32 + quad * 8]);
        s0 = __builtin_amdgcn_mfma_f32_16x16x32_bf16(qf[kk], b0, s0, 0, 0, 0);
        s1 = __builtin_amdgcn_mfma_f32_16x16x32_bf16(qf[kk], b1, s1, 0, 0, 0);
      }
      // mask + scale
      float sv0[4], sv1[4];
#pragma unroll
      for (int e = 0; e < 4; e++) {
        int qi = qw + quad * 4 + e;
        int k0i = kt + l16, k1i = kt + 16 + l16;
        bool a0 = (k0i <= qi) && (qi - k0i < WIN_);
        bool a1 = (k1i <= qi) && (qi - k1i < WIN_);
        sv0[e] = a0 ? s0[e] * scale : -1e30f;
        sv1[e] = a1 ? s1[e] * scale : -1e30f;
      }
      // online softmax
      float alpha[4];
#pragma unroll
      for (int e = 0; e < 4; e++) {
        float mx = fmaxf(sv0[e], sv1[e]);
#pragma unroll
        for (int off = 1; off < 16; off <<= 1)
          mx = fmaxf(mx, __shfl_xor(mx, off, 64));
        float mn = fmaxf(m_i[e], mx);
        alpha[e] = __expf(m_i[e] - mn);
        m_i[e] = mn;
        float p0 = __expf(sv0[e] - mn);
        float p1 = __expf(sv1[e] - mn);
        sv0[e] = p0; sv1[e] = p1;
        float rs = p0 + p1;
#pragma unroll
        for (int off = 1; off < 16; off <<= 1)
          rs += __shfl_xor(rs, off, 64);
        l_i[e] = l_i[e] * alpha[e] + rs;
      }
      // P (C-layout) -> LDS -> A-layout bf16
      u16* P = &Ps[wave][0];
#pragma unroll
      for (int e = 0; e < 4; e++) {
        P[(quad * 4 + e) * 40 + l16]      = f2b(sv0[e]);
        P[(quad * 4 + e) * 40 + 16 + l16] = f2b(sv1[e]);
      }
      bf16x8 pa = *(const bf16x8*)(&P[l16 * 40 + quad * 8]);
      // rescale O, then O += P V
#pragma unroll
      for (int nj = 0; nj < 8; nj++)
#pragma unroll
        for (int e = 0; e < 4; e++) o_acc[nj][e] *= alpha[e];
#pragma unroll
      for (int nj = 0; nj < 8; nj++) {
        bf16x8 bv = *(const bf16x8*)(&Vs[(nj * 16 + l16) * 40 + quad * 8]);
        o_acc[nj] = __builtin_amdgcn_mfma_f32_16x16x32_bf16(pa, bv, o_acc[nj], 0, 0, 0);
      }
    }
  }

  // epilogue: O /= l, store bf16 [B,S,NH,HD]
  size_t obase = (((size_t)(b * S_ + qw + quad * 4)) * NH_ + h) * HD_;
#pragma unroll
  for (int nj = 0; nj < 8; nj++) {
#pragma unroll
    for (int e = 0; e < 4; e++) {
      float v = o_acc[nj][e] / l_i[e];
      O[obase + (size_t)e * NH_ * HD_ + nj * 16 + l16] = f2b(v);
    }
  }
}

// ---------------- launch ----------------
extern "C" void kernel_launch(void* const* d_in, const int* in_sizes, int n_in,
                              void* d_out, int out_size, void* d_ws, size_t ws_size,
                              hipStream_t stream) {
  const float* x  = (const float*)d_in[0];
  const float* Wq = (const float*)d_in[1];
  const float* Wk = (const float*)d_in[2];
  const float* Wv = (const float*)d_in[3];
  const float* Wo = (const float*)d_in[4];
  const int*  pos = (const int*)d_in[5];
  float* out = (float*)d_out;

  const size_t BS = (size_t)B_ * S_;  // 4096
  char* p = (char*)d_ws;
  u16* xb  = (u16*)p; p += BS * H_ * 2;                    // 32 MB (reused as attn-out)
  u16* W32 = (u16*)p; p += (size_t)H_ * H_ * 2;            // 32 MB (Wq then Wo)
  u16* W8  = (u16*)p; p += (size_t)NKV_ * HD_ * H_ * 2;    // 8 MB  (Wk then Wv)
  u16* Qb  = (u16*)p; p += BS * NH_ * HD_ * 2;             // 32 MB
  u16* Kb  = (u16*)p; p += BS * NKV_ * HD_ * 2;            // 8 MB
  u16* Vb  = (u16*)p; p += BS * NKV_ * HD_ * 2;            // 8 MB
  u16* Ob  = xb;

  auto cvt = [&](const float* src, u16* dst, size_t n) {
    int n4 = (int)(n / 4);
    cvt_bf16<<<dim3((n4 + 255) / 256), dim3(256), 0, stream>>>(src, dst, n4);
  };

  cvt(x, xb, BS * H_);
  cvt(Wq, W32, (size_t)H_ * H_);
  gemm_bt<u16><<<dim3(H_ / 128, BS / 128), dim3(256), 0, stream>>>(
      xb, W32, Qb, (int)BS, H_, H_);
  cvt(Wk, W8, (size_t)NKV_ * HD_ * H_);
  gemm_bt<u16><<<dim3(NKV_ * HD_ / 128, BS / 128), dim3(256), 0, stream>>>(
      xb, W8, Kb, (int)BS, NKV_ * HD_, H_);
  cvt(Wv, W8, (size_t)NKV_ * HD_ * H_);
  gemm_bt<u16><<<dim3(NKV_ * HD_ / 128, BS / 128), dim3(256), 0, stream>>>(
      xb, W8, Vb, (int)BS, NKV_ * HD_, H_);

  rope_k<<<dim3(NH_, S_, B_), dim3(64), 0, stream>>>(Qb, pos, NH_);
  rope_k<<<dim3(NKV_, S_, B_), dim3(64), 0, stream>>>(Kb, pos, NKV_);

  attn_k<<<dim3(S_ / 64, NH_, B_), dim3(256), 0, stream>>>(Qb, Kb, Vb, Ob);

  cvt(Wo, W32, (size_t)H_ * H_);
  gemm_bt<float><<<dim3(H_ / 128, BS / 128), dim3(256), 0, stream>>>(
      Ob, W32, out, (int)BS, H_, H_);
}

// Round 3
// 1028.048 us; speedup vs baseline: 1.2388x; 1.2388x over previous
//
#include <hip/hip_runtime.h>
#include <hip/hip_bf16.h>
#include <cmath>

typedef unsigned short u16;
typedef __attribute__((ext_vector_type(8))) short bf16x8;
typedef __attribute__((ext_vector_type(4))) float f32x4;

#define B_    2
#define S_    2048
#define H_    4096
#define NH_   32
#define NKV_  8
#define HD_   128
#define WIN_  1024

__device__ __forceinline__ u16 f2b(float f) {
  union { float f; unsigned u; } v; v.f = f;
  unsigned r = v.u + 0x7fffu + ((v.u >> 16) & 1u);
  return (u16)(r >> 16);
}
__device__ __forceinline__ float b2f(u16 h) {
  union { unsigned u; float f; } v; v.u = ((unsigned)h) << 16;
  return v.f;
}

__device__ __forceinline__ void storeC(float* p, float v) { *p = v; }
__device__ __forceinline__ void storeC(u16* p, float v)   { *p = f2b(v); }

// async global->LDS, 16B per lane; LDS dest must be wave-base + lane*16
__device__ __forceinline__ void gl2lds(const u16* g, u16* l) {
  __builtin_amdgcn_global_load_lds(
      (const __attribute__((address_space(1))) unsigned int*)(g),
      (__attribute__((address_space(3))) unsigned int*)(l), 16, 0, 0);
}

// ---------------- fp32 -> bf16 conversion ----------------
__global__ __launch_bounds__(256) void cvt_bf16(const float* __restrict__ s,
                                                u16* __restrict__ d, int n4) {
  int i = blockIdx.x * 256 + threadIdx.x;
  if (i < n4) {
    float4 v = ((const float4*)s)[i];
    ushort4 o;
    o.x = f2b(v.x); o.y = f2b(v.y); o.z = f2b(v.z); o.w = f2b(v.w);
    ((ushort4*)d)[i] = o;
  }
}

// ---- GEMM: C[M,N] = A[M,K] * W[N,K]^T, bf16 in, m97-style async staging ----
// BM x 128 tile, BK=32, 4 waves (2x2); unpadded LDS (global_load_lds dest).
template <int BM, typename OutT>
__global__ __launch_bounds__(256) void gemm_bt(const u16* __restrict__ A,
                                               const u16* __restrict__ W,
                                               OutT* __restrict__ C,
                                               int M, int N, int K) {
  __shared__ u16 As[BM * 32];
  __shared__ u16 Bs[128 * 32];
  const int t = threadIdx.x;
  const int lane = t & 63, wave = t >> 6;
  const int quad = lane >> 4, l16 = lane & 15;
  const int wm = wave >> 1, wn = wave & 1;
  constexpr int WM = BM / 2;       // wave m-extent
  constexpr int MI = WM / 16;      // m-frags per wave
  const size_t m0 = (size_t)blockIdx.y * BM, n0 = (size_t)blockIdx.x * 128;

  f32x4 acc[MI][4] = {};
  const int srow = lane >> 2, skc = lane & 3;  // 16 rows x 4 chunks per instr

  for (int k0 = 0; k0 < K; k0 += 32) {
    __syncthreads();
#pragma unroll
    for (int i = 0; i < BM / 64; i++) {
      int row = wave * (BM / 4) + i * 16 + srow;
      gl2lds(A + (m0 + row) * K + k0 + skc * 8, &As[row * 32 + skc * 8]);
    }
#pragma unroll
    for (int i = 0; i < 2; i++) {
      int row = wave * 32 + i * 16 + srow;
      gl2lds(W + (n0 + row) * K + k0 + skc * 8, &Bs[row * 32 + skc * 8]);
    }
    __syncthreads();
    bf16x8 af[MI], bfr[4];
#pragma unroll
    for (int i = 0; i < MI; i++)
      af[i] = *(const bf16x8*)(&As[(wm * WM + i * 16 + l16) * 32 + quad * 8]);
#pragma unroll
    for (int i = 0; i < 4; i++)
      bfr[i] = *(const bf16x8*)(&Bs[(wn * 64 + i * 16 + l16) * 32 + quad * 8]);
#pragma unroll
    for (int mi = 0; mi < MI; mi++)
#pragma unroll
      for (int nj = 0; nj < 4; nj++)
        acc[mi][nj] = __builtin_amdgcn_mfma_f32_16x16x32_bf16(
            af[mi], bfr[nj], acc[mi][nj], 0, 0, 0);
  }

#pragma unroll
  for (int mi = 0; mi < MI; mi++) {
    size_t rbase = m0 + wm * WM + mi * 16 + quad * 4;
#pragma unroll
    for (int nj = 0; nj < 4; nj++) {
      size_t col = n0 + wn * 64 + nj * 16 + l16;
#pragma unroll
      for (int e = 0; e < 4; e++)
        storeC(&C[(rbase + e) * N + col], acc[mi][nj][e]);
    }
  }
}

// ---------------- RoPE in-place on bf16 [B*S, nh, 128] ----------------
__global__ __launch_bounds__(256) void rope_k(u16* __restrict__ X,
                                              const int* __restrict__ pos,
                                              int log2nh) {
  int idx = blockIdx.x * 256 + threadIdx.x;
  int i = idx & 63;
  int bsh = idx >> 6;
  int h = bsh & ((1 << log2nh) - 1);
  int bs = bsh >> log2nh;
  int p = pos[bs];
  float inv = exp2f(-(float)i * (13.287712379549449f / 64.0f));
  float ang = (float)p * inv;
  float sn, c;
  sincosf(ang, &sn, &c);
  size_t base = ((((size_t)bs) << log2nh) + h) * HD_;
  float x1 = b2f(X[base + i]), x2 = b2f(X[base + i + 64]);
  X[base + i]      = f2b(x1 * c - x2 * sn);
  X[base + i + 64] = f2b(x2 * c + x1 * sn);
}

// ------------- V transpose: [B,S,NKV,HD] -> [B,NKV,HD,S] -------------
__global__ __launch_bounds__(256) void transpose_v(const u16* __restrict__ V,
                                                   u16* __restrict__ Vt) {
  __shared__ u16 tile[64][72];
  int s0 = blockIdx.x * 64, d0 = blockIdx.y * 64, bh = blockIdx.z;
  int b = bh >> 3, hk = bh & 7;
  int t = threadIdx.x;
  int r = t >> 3, c = t & 7;
#pragma unroll
  for (int i = 0; i < 2; i++) {
    int row = r + i * 32;
    uint4 v = *(const uint4*)(V + (((size_t)(b * S_ + s0 + row)) * NKV_ + hk) * HD_ + d0 + c * 8);
    *(uint4*)(&tile[row][c * 8]) = v;
  }
  __syncthreads();
#pragma unroll
  for (int i = 0; i < 2; i++) {
    int d = r + i * 32;
    u16 tmp[8];
#pragma unroll
    for (int j = 0; j < 8; j++) tmp[j] = tile[c * 8 + j][d];
    *(uint4*)(Vt + ((size_t)bh * HD_ + d0 + d) * S_ + s0 + c * 8) = *(uint4*)tmp;
  }
}

// ---------------- flash attention, sliding window ----------------
// grid (S/64, NH, B), 256 threads; wave w handles 16 q rows.
__global__ __launch_bounds__(256) void attn_k(const u16* __restrict__ Q,
                                              const u16* __restrict__ K,
                                              const u16* __restrict__ Vt,
                                              u16* __restrict__ O) {
  __shared__ u16 Ks[32 * 136];     // [key][d], pad 8
  __shared__ u16 Vs[128 * 40];     // [d][key], pad 8
  __shared__ u16 Ps[4][16 * 40];   // per-wave P scratch [q][key], pad 8

  const int t = threadIdx.x, wave = t >> 6, lane = t & 63;
  const int quad = lane >> 4, l16 = lane & 15;
  const int q0 = blockIdx.x * 64, h = blockIdx.y, b = blockIdx.z;
  const int hk = h >> 2;
  const int qw = q0 + wave * 16;
  const float scale = 0.08838834764831845f;  // 1/sqrt(128)

  bf16x8 qf[4];
  {
    size_t qrow = (((size_t)(b * S_ + qw + l16)) * NH_ + h) * HD_;
#pragma unroll
    for (int kk = 0; kk < 4; kk++)
      qf[kk] = *(const bf16x8*)(Q + qrow + kk * 32 + quad * 8);
  }

  f32x4 o_acc[8] = {};
  float m_i[4], l_i[4];
#pragma unroll
  for (int e = 0; e < 4; e++) { m_i[e] = -1e30f; l_i[e] = 0.0f; }

  int lo = q0 - (WIN_ - 1); if (lo < 0) lo = 0;
  const int lo_t = lo & ~31;
  const size_t vbase = ((size_t)(b * NKV_ + hk)) * HD_ * S_;

  for (int kt = lo_t; kt <= q0 + 63; kt += 32) {
    __syncthreads();
    // stage K tile [32 keys][128 d], vectorized
#pragma unroll
    for (int i = 0; i < 2; i++) {
      int c = t + 256 * i;
      int row = c >> 4, dc = c & 15;
      uint4 v = *(const uint4*)(K + (((size_t)(b * S_ + kt + row)) * NKV_ + hk) * HD_ + dc * 8);
      *(uint4*)(&Ks[row * 136 + dc * 8]) = v;
    }
    // stage V^T tile [128 d][32 keys], vectorized from pre-transposed Vt
#pragma unroll
    for (int i = 0; i < 2; i++) {
      int c = t + 256 * i;
      int d = c >> 2, kc = c & 3;
      uint4 v = *(const uint4*)(Vt + vbase + (size_t)d * S_ + kt + kc * 8);
      *(uint4*)(&Vs[d * 40 + kc * 8]) = v;
    }
    __syncthreads();

    if (kt <= qw + 15 && kt + 31 >= qw - (WIN_ - 1)) {
      f32x4 s0 = {}, s1 = {};
#pragma unroll
      for (int kk = 0; kk < 4; kk++) {
        bf16x8 b0 = *(const bf16x8*)(&Ks[(l16) * 136 + kk * 32 + quad * 8]);
        bf16x8 b1 = *(const bf16x8*)(&Ks[(16 + l16) * 136 + kk * 32 + quad * 8]);
        s0 = __builtin_amdgcn_mfma_f32_16x16x32_bf16(qf[kk], b0, s0, 0, 0, 0);
        s1 = __builtin_amdgcn_mfma_f32_16x16x32_bf16(qf[kk], b1, s1, 0, 0, 0);
      }
      float sv0[4], sv1[4];
#pragma unroll
      for (int e = 0; e < 4; e++) {
        int qi = qw + quad * 4 + e;
        int k0i = kt + l16, k1i = kt + 16 + l16;
        bool a0 = (k0i <= qi) && (qi - k0i < WIN_);
        bool a1 = (k1i <= qi) && (qi - k1i < WIN_);
        sv0[e] = a0 ? s0[e] * scale : -1e30f;
        sv1[e] = a1 ? s1[e] * scale : -1e30f;
      }
      float alpha[4];
#pragma unroll
      for (int e = 0; e < 4; e++) {
        float mx = fmaxf(sv0[e], sv1[e]);
#pragma unroll
        for (int off = 1; off < 16; off <<= 1)
          mx = fmaxf(mx, __shfl_xor(mx, off, 64));
        float mn = fmaxf(m_i[e], mx);
        alpha[e] = __expf(m_i[e] - mn);
        m_i[e] = mn;
        float p0 = __expf(sv0[e] - mn);
        float p1 = __expf(sv1[e] - mn);
        sv0[e] = p0; sv1[e] = p1;
        float rs = p0 + p1;
#pragma unroll
        for (int off = 1; off < 16; off <<= 1)
          rs += __shfl_xor(rs, off, 64);
        l_i[e] = l_i[e] * alpha[e] + rs;
      }
      // P (C-layout) -> LDS -> A-layout bf16
      u16* P = &Ps[wave][0];
#pragma unroll
      for (int e = 0; e < 4; e++) {
        P[(quad * 4 + e) * 40 + l16]      = f2b(sv0[e]);
        P[(quad * 4 + e) * 40 + 16 + l16] = f2b(sv1[e]);
      }
      bf16x8 pa = *(const bf16x8*)(&P[l16 * 40 + quad * 8]);
#pragma unroll
      for (int nj = 0; nj < 8; nj++)
#pragma unroll
        for (int e = 0; e < 4; e++) o_acc[nj][e] *= alpha[e];
#pragma unroll
      for (int nj = 0; nj < 8; nj++) {
        bf16x8 bv = *(const bf16x8*)(&Vs[(nj * 16 + l16) * 40 + quad * 8]);
        o_acc[nj] = __builtin_amdgcn_mfma_f32_16x16x32_bf16(pa, bv, o_acc[nj], 0, 0, 0);
      }
    }
  }

  size_t obase = (((size_t)(b * S_ + qw + quad * 4)) * NH_ + h) * HD_;
#pragma unroll
  for (int nj = 0; nj < 8; nj++) {
#pragma unroll
    for (int e = 0; e < 4; e++) {
      float v = o_acc[nj][e] / l_i[e];
      O[obase + (size_t)e * NH_ * HD_ + nj * 16 + l16] = f2b(v);
    }
  }
}

// ---------------- launch ----------------
extern "C" void kernel_launch(void* const* d_in, const int* in_sizes, int n_in,
                              void* d_out, int out_size, void* d_ws, size_t ws_size,
                              hipStream_t stream) {
  const float* x  = (const float*)d_in[0];
  const float* Wq = (const float*)d_in[1];
  const float* Wk = (const float*)d_in[2];
  const float* Wv = (const float*)d_in[3];
  const float* Wo = (const float*)d_in[4];
  const int*  pos = (const int*)d_in[5];
  float* out = (float*)d_out;

  const size_t BS = (size_t)B_ * S_;  // 4096
  const size_t MB = 1024 * 1024;
  char* p = (char*)d_ws;
  u16* xb  = (u16*)(p);             // 32 MB: x bf16; later Wo bf16
  u16* W32 = (u16*)(p + 32 * MB);   // 32 MB: Wq bf16; later attn-out Ob
  u16* W8  = (u16*)(p + 64 * MB);   // 8 MB: Wk, then Wv, then Vt
  u16* Qb  = (u16*)(p + 72 * MB);   // 32 MB
  u16* Kb  = (u16*)(p + 104 * MB);  // 8 MB
  u16* Vb  = (u16*)(p + 112 * MB);  // 8 MB
  u16* WoB = xb;
  u16* Ob  = W32;
  u16* Vt  = W8;

  auto cvt = [&](const float* src, u16* dst, size_t n) {
    int n4 = (int)(n / 4);
    cvt_bf16<<<dim3((n4 + 255) / 256), dim3(256), 0, stream>>>(src, dst, n4);
  };

  cvt(x, xb, BS * H_);
  cvt(Wq, W32, (size_t)H_ * H_);
  gemm_bt<128, u16><<<dim3(H_ / 128, BS / 128), dim3(256), 0, stream>>>(
      xb, W32, Qb, (int)BS, H_, H_);
  cvt(Wk, W8, (size_t)NKV_ * HD_ * H_);
  gemm_bt<64, u16><<<dim3(NKV_ * HD_ / 128, BS / 64), dim3(256), 0, stream>>>(
      xb, W8, Kb, (int)BS, NKV_ * HD_, H_);
  cvt(Wv, W8, (size_t)NKV_ * HD_ * H_);
  gemm_bt<64, u16><<<dim3(NKV_ * HD_ / 128, BS / 64), dim3(256), 0, stream>>>(
      xb, W8, Vb, (int)BS, NKV_ * HD_, H_);

  rope_k<<<dim3((int)(BS * NH_ * 64 / 256)), dim3(256), 0, stream>>>(Qb, pos, 5);
  rope_k<<<dim3((int)(BS * NKV_ * 64 / 256)), dim3(256), 0, stream>>>(Kb, pos, 3);

  transpose_v<<<dim3(S_ / 64, HD_ / 64, B_ * NKV_), dim3(256), 0, stream>>>(Vb, Vt);

  attn_k<<<dim3(S_ / 64, NH_, B_), dim3(256), 0, stream>>>(Qb, Kb, Vt, Ob);

  cvt(Wo, WoB, (size_t)H_ * H_);
  gemm_bt<128, float><<<dim3(H_ / 128, BS / 128), dim3(256), 0, stream>>>(
      Ob, WoB, out, (int)BS, H_, H_);
}